// Round 5
// baseline (3892.586 us; speedup 1.0000x reference)
//
#include <hip/hip_runtime.h>
#include <hip/hip_fp16.h>

#define B_ 32
#define T_ 4096
#define F_ 128
#define C_ 256
#define K_ 128
#define FC_ 384

typedef __attribute__((ext_vector_type(8))) short s8v;
typedef __attribute__((ext_vector_type(4))) float f4v;
typedef __attribute__((ext_vector_type(4))) int   i4v;

#define MFMA16(a,b,c) __builtin_amdgcn_mfma_f32_16x16x32_bf16((a),(b),(c),0,0,0)

#define LOG2E  1.442695041f
#define LOG2E2 2.885390082f
#define LN2    0.6931471806f

// ---- workspace layout (bytes) ----
#define WS_WSCAN 0u        // i8 scan weights, per-channel dword-packed: 512*64*4 = 131072
#define WS_SMAX  131072u   // 512 f32 per-column |w|max (g:0-255, a:256-511)
#define WS_W1F   262144u   // 12288 * 16 = 196608
#define WS_OWF   458752u   // 4096 * 16 = 65536
#define WS_BIAS1 524288u   // 768 * 4 = 3072
#define WS_CARRY 527360u   // n,d,h,am(scaled by log2e) : 4 * 8192 f32 = 131072
#define WS_DYN   658432u   // pre chunk (49152*Tc B) then hall chunk (16384*Tc B)

__device__ __forceinline__ unsigned short f2bf(float f){
  unsigned u = __float_as_uint(f);
  u += 0x7fffu + ((u>>16)&1u);     // round-to-nearest-even
  return (unsigned short)(u>>16);
}
__device__ __forceinline__ float h2f(unsigned short s){
  __half_raw r; r.x = s; return __half2float((__half)r);
}
__device__ __forceinline__ float fexp2(float x){
#if __has_builtin(__builtin_amdgcn_exp2f)
  return __builtin_amdgcn_exp2f(x);
#else
  return __expf(x*0.69314718056f);
#endif
}
__device__ __forceinline__ int dot4(int a, int b, int c){
#if __has_builtin(__builtin_amdgcn_sdot4)
  return __builtin_amdgcn_sdot4(a, b, c, false);
#else
  int r = c;
  r += (int)(char)(a      ) * (int)(char)(b      );
  r += (int)(char)(a >> 8 ) * (int)(char)(b >> 8 );
  r += (int)(char)(a >> 16) * (int)(char)(b >> 16);
  r += (int)(char)(a >> 24) * (int)(char)(b >> 24);
  return r;
#endif
}

// ---------------- per-column |w|max for i8 quant of scan weights ----------------
__global__ __launch_bounds__(256) void scale_kernel(
    const float* __restrict__ g_w, const float* __restrict__ a_w, char* __restrict__ ws)
{
  int id = blockIdx.x*256 + threadIdx.x;     // 512
  if (id >= 512) return;
  const float* src = (id < 256) ? g_w : a_w;
  int c = id & 255;
  float m = 0.0f;
  #pragma unroll 8
  for (int k=0;k<256;++k) m = fmaxf(m, fabsf(src[c*FC_ + F_ + k]));
  ((float*)(ws + WS_SMAX))[id] = fmaxf(m, 1e-30f);
}

// ---------------- weight packing ----------------
// scan weights: per-channel packed i8 dwords for v_dot4_i32_i8 GEMV.
// dword[(mat*256+c)*64 + kd], byte j = quant(W[c][F_+4kd+j]); mat 0=g, 1=a.
__global__ __launch_bounds__(256) void pack_kernel(
    const float* __restrict__ g_w, const float* __restrict__ u_w, const float* __restrict__ a_w,
    const float* __restrict__ g_b, const float* __restrict__ u_b, const float* __restrict__ o_w,
    char* __restrict__ ws)
{
  int id = blockIdx.x*256 + threadIdx.x;
  const float* smax = (const float*)(ws + WS_SMAX);
  unsigned short* w1f   = (unsigned short*)(ws + WS_W1F);
  unsigned short* owf   = (unsigned short*)(ws + WS_OWF);
  float* bias1          = (float*)(ws + WS_BIAS1);
  if (id < 8192){
    // thread id -> (mc = mat*256+c, i4); writes dwords kd = i4*4 .. i4*4+3
    int i4 = id & 15, mc = id >> 4;
    int c = mc & 255, mat = mc >> 8;
    const float* src = mat ? a_w : g_w;
    float inv = 127.0f / smax[mat*256 + c];
    int w32[4] = {0,0,0,0};
    #pragma unroll
    for (int j=0;j<16;++j){
      int k = i4*16 + j;
      int q8 = __float2int_rn(src[c*FC_ + F_ + k] * inv);
      w32[j>>2] |= (q8 & 0xff) << (8*(j&3));
    }
    int* dst = (int*)(ws + WS_WSCAN) + mc*64 + i4*4;
    dst[0]=w32[0]; dst[1]=w32[1]; dst[2]=w32[2]; dst[3]=w32[3];
  } else if (id < 8192+12288){
    // ph1 weights rows n: [0,256)=u_w, [256,512)=g_w x-part (*2log2e), [512,768)=a_w x-part (*log2e)
    int id2 = id - 8192;
    int l = id2 & 63, kc = (id2>>6)&3, nt = id2>>8;
    int n = nt*16 + (l&15);
    int kb = kc*32 + (l>>4)*8;
    float sc = (n < 256) ? 1.0f : (n < 512) ? LOG2E2 : LOG2E;
    #pragma unroll
    for (int j=0;j<8;++j){
      int k = kb + j;
      float v = (n < 256) ? u_w[n*F_ + k]
              : (n < 512) ? g_w[(n-256)*FC_ + k]
                          : a_w[(n-512)*FC_ + k];
      w1f[id2*8+j] = f2bf(v*sc);
    }
  } else if (id < 8192+12288+4096){
    int id3 = id - (8192+12288);
    int l = id3 & 63, kc = (id3>>6)&7, nt = id3>>9;
    int n = nt*16 + (l&15);
    int kb = kc*32 + (l>>4)*8;
    #pragma unroll
    for (int j=0;j<8;++j)
      owf[id3*8+j] = f2bf(o_w[n*C_ + kb + j]);
  } else if (id < 8192+12288+4096+768){
    int i = id - (8192+12288+4096);
    bias1[i] = (i<256) ? u_b[i] : (i<512 ? g_b[i-256]*LOG2E2 : 0.0f);
  }
}

// ---------------- init: carry <- initial state (a_max scaled by log2e) ----------------
__global__ __launch_bounds__(256) void init_kernel(
    const float* __restrict__ n0, const float* __restrict__ d0,
    const float* __restrict__ h0, const float* __restrict__ am0, char* __restrict__ ws)
{
  int id = blockIdx.x*256 + threadIdx.x;   // 8192
  float* c = (float*)(ws + WS_CARRY);
  c[id]        = n0[id];
  c[8192+id]   = d0[id];
  c[16384+id]  = h0[id];
  c[24576+id]  = am0[id]*LOG2E;
}

// ---------------- ph1: pre = x @ [u_w; g_w_x*2log2e; a_w_x*log2e]^T + bias (fp16) --------
__global__ __launch_bounds__(256) void ph1_kernel(const float* __restrict__ x, char* __restrict__ ws,
                                                  int t0, int Tc, int lgT16)
{
  const s8v* w1f = (const s8v*)(ws + WS_W1F);
  const float* bias1 = (const float*)(ws + WS_BIAS1);
  __half* pre = (__half*)(ws + WS_DYN);
  int tid = threadIdx.x;
  int wv = tid>>6, l = tid&63, q = l>>4, col = l&15;
  int wid = blockIdx.x*4 + wv;
  int b  = wid >> lgT16;
  int tb = (wid & ((1<<lgT16)-1))*16;
  s8v af[4];
  const float* xr = x + ((size_t)b*T_ + t0 + tb + col)*F_ + q*8;
  #pragma unroll
  for (int kc=0;kc<4;++kc){
    const float* p = xr + kc*32;
    float4 p0 = *(const float4*)(p);
    float4 p1 = *(const float4*)(p+4);
    s8v a;
    a[0]=(short)f2bf(p0.x); a[1]=(short)f2bf(p0.y); a[2]=(short)f2bf(p0.z); a[3]=(short)f2bf(p0.w);
    a[4]=(short)f2bf(p1.x); a[5]=(short)f2bf(p1.y); a[6]=(short)f2bf(p1.z); a[7]=(short)f2bf(p1.w);
    af[kc]=a;
  }
  for (int nt=0;nt<48;++nt){
    f4v acc = {0.f,0.f,0.f,0.f};
    #pragma unroll
    for (int kc=0;kc<4;++kc)
      acc = MFMA16(af[kc], w1f[(nt*4+kc)*64 + l], acc);
    int cg = nt*16 + col;
    float bs = bias1[cg];
    #pragma unroll
    for (int i=0;i<4;++i){
      int rl = tb + q*4 + i;
      pre[(size_t)(b*Tc + rl)*768 + cg] = __float2half(acc[i] + bs);
    }
  }
}

// ---------------- scan: sequential recurrence, 1 batch row per block ----------------
// R5 (= R4 retry, hardened): R1-R3 were bound by per-step WEIGHT REFETCH from L2 — the
// compiler sank the loop-invariant weight loads into the loop (VGPR_Count 84 < the 128
// regs the weights need; ~970 cyc/step of L2 traffic at 512B/lane). Fix: opaque identity
// asm pins each weight DWORD (scalar int operands only — vector-typed "v" operands were
// the sole untested delta in the R4 run that failed) so the compiler cannot rematerialize
// the loads. Step path: 16 broadcast ds_read_b128 -> 128 sdot4 (8 chains) -> tail -> barrier.
__global__ __launch_bounds__(256,1) void scan_kernel(char* __restrict__ ws, int Tc)
{
  __shared__ __align__(16) char h8buf[2][256];
  const i4v* wp = (const i4v*)(ws + WS_WSCAN);   // i4v index: (mat*256+c)*16 + i
  const float* smax = (const float*)(ws + WS_SMAX);
  const unsigned short* prbu = (const unsigned short*)(ws + WS_DYN);
  unsigned short* hall = (unsigned short*)(ws + WS_DYN + 49152u*(unsigned)Tc);
  float* carry = (float*)(ws + WS_CARRY);
  int tid = threadIdx.x;
  int wv = tid>>6, l = tid&63, q = l>>4, col = l&15;
  int b = blockIdx.x;
  int c = wv*64 + q*16 + col;          // this lane's channel

  // one-time load of per-lane packed weights, then PIN each dword in a VGPR (128 regs)
  int wgr[64], war[64];
  #pragma unroll
  for (int i=0;i<16;++i){
    i4v g4 = wp[(size_t)c*16 + i];
    i4v a4 = wp[(size_t)(256 + c)*16 + i];
    wgr[i*4+0]=g4[0]; wgr[i*4+1]=g4[1]; wgr[i*4+2]=g4[2]; wgr[i*4+3]=g4[3];
    war[i*4+0]=a4[0]; war[i*4+1]=a4[1]; war[i*4+2]=a4[2]; war[i*4+3]=a4[3];
  }
  #pragma unroll
  for (int i=0;i<64;++i){
    asm volatile("" : "+v"(wgr[i]));
    asm volatile("" : "+v"(war[i]));
  }
  float gsc = smax[c]     * (LOG2E2/16129.0f);   // maxg/(127*127) * 2log2e
  float asc = smax[256+c] * (LOG2E /16129.0f);

  int gi = b*C_ + c;
  float cn = carry[gi], cd = carry[8192+gi], cm = carry[24576+gi];
  h8buf[0][c] = (char)__float2int_rn(carry[16384+gi]*127.0f);
  __syncthreads();

  const size_t prb = (size_t)b*Tc*768;
  unsigned short* hrow = hall + (size_t)b*Tc*C_ + c;

  // prefetch pre for t=0..3 (4-deep; loads stay in flight across lgkm-only barriers)
  unsigned short su[4], sg[4], sa[4];
  #pragma unroll
  for (int i=0;i<4;++i){
    size_t o = prb + (size_t)i*768;
    su[i]=prbu[o + c]; sg[i]=prbu[o + 256+c]; sa[i]=prbu[o + 512+c];
  }

  #pragma unroll 1
  for (int t=0;t<Tc;t+=4){
    #pragma unroll
    for (int ph=0; ph<4; ++ph){
      int s = t + ph;
      const char* hc = h8buf[ph&1];
      char* hn = h8buf[(ph&1)^1];
      const i4v* hv4 = (const i4v*)hc;
      // consume slot ph early, then issue refill for s+4 (overlaps the dot chains)
      float fu = h2f(su[ph]), fg = h2f(sg[ph]), fa = h2f(sa[ph]);
      {
        int nxt = (s+4 < Tc) ? s+4 : s;
        size_t o = prb + (size_t)nxt*768;
        su[ph]=prbu[o + c]; sg[ph]=prbu[o + 256+c]; sa[ph]=prbu[o + 512+c];
      }
      // GEMV: 16 broadcast ds_read_b128 + 128 sdot4 in 8 chains
      int ag0=0, ag1=0, ag2=0, ag3=0;
      int aa0=0, aa1=0, aa2=0, aa3=0;
      #pragma unroll
      for (int i=0;i<16;++i){
        i4v h4 = hv4[i];
        ag0 = dot4(h4[0], wgr[i*4+0], ag0);
        ag1 = dot4(h4[1], wgr[i*4+1], ag1);
        ag2 = dot4(h4[2], wgr[i*4+2], ag2);
        ag3 = dot4(h4[3], wgr[i*4+3], ag3);
        aa0 = dot4(h4[0], war[i*4+0], aa0);
        aa1 = dot4(h4[1], war[i*4+1], aa1);
        aa2 = dot4(h4[2], war[i*4+2], aa2);
        aa3 = dot4(h4[3], war[i*4+3], aa3);
      }
      // dequant + scalar recurrence (all pre-scaled: exp -> exp2 direct)
      float g = (float)((ag0+ag1)+(ag2+ag3)) * gsc + fg;     // = 2log2e * g_raw
      float a = (float)((aa0+aa1)+(aa2+aa3)) * asc + fa;     // = log2e * a_raw

      float z = fu * (1.0f - 2.0f*__builtin_amdgcn_rcpf(fexp2(g) + 1.0f));  // fu*tanh(g_raw)
      float anew = fmaxf(cm,a);
      float dmin = fminf(cm,a);
      float e = fexp2(dmin-anew);      // one side is exp(0)=1
      bool ge = (a>=cm);
      float ed = ge? e : 1.0f;
      float es = ge? 1.0f : e;
      cn = cn*ed + z*es;
      cd = fmaf(cd,ed,es);
      float hv = 1.0f - 2.0f*__builtin_amdgcn_rcpf(fexp2(LOG2E2*(cn*__builtin_amdgcn_rcpf(cd))) + 1.0f);
      cm = anew;
      hn[c] = (char)__float2int_rn(hv*127.0f);
      hrow[(size_t)s*C_] = f2bf(hv);
      // LDS-only drain + raw barrier: global loads/stores stay in flight.
      asm volatile("s_waitcnt lgkmcnt(0)" ::: "memory");
      __builtin_amdgcn_s_barrier();
      asm volatile("" ::: "memory");
    }
  }
  // write back carry
  carry[gi] = cn; carry[8192+gi] = cd; carry[24576+gi] = cm;
  carry[16384+gi] = 1.0f - 2.0f*__builtin_amdgcn_rcpf(fexp2(LOG2E2*(cn*__builtin_amdgcn_rcpf(cd))) + 1.0f);
}

// ---------------- ph3: outs = h @ o_w^T + o_b ----------------
__global__ __launch_bounds__(256) void ph3_kernel(const float* __restrict__ o_b,
                                                  char* __restrict__ ws, float* __restrict__ out,
                                                  int t0, int Tc, int lgT16)
{
  const s8v* owf = (const s8v*)(ws + WS_OWF);
  const unsigned short* hall = (const unsigned short*)(ws + WS_DYN + 49152u*(unsigned)Tc);
  int tid = threadIdx.x;
  int wv = tid>>6, l = tid&63, q=l>>4, col=l&15;
  int wid = blockIdx.x*4 + wv;
  int bb = wid >> lgT16;
  int tt = (wid & ((1<<lgT16)-1))*16;
  const unsigned short* src = hall + ((size_t)bb*Tc + tt)*C_;
  s8v af[8];
  #pragma unroll
  for (int kc=0;kc<8;++kc)
    af[kc] = *(const s8v*)(src + (size_t)col*C_ + kc*32 + q*8);
  #pragma unroll
  for (int nt=0;nt<8;++nt){
    f4v acc={0.f,0.f,0.f,0.f};
    #pragma unroll
    for (int kc=0;kc<8;++kc)
      acc = MFMA16(af[kc], owf[(nt*8+kc)*64 + l], acc);
    int k = nt*16+col;
    float bs = o_b[k];
    #pragma unroll
    for (int i=0;i<4;++i)
      out[((size_t)bb*T_ + t0 + tt + q*4 + i)*K_ + k] = acc[i] + bs;
  }
}

// ---------------- finalize: final states -> out tail (unscale a_max) ----------------
__global__ __launch_bounds__(256) void fin_kernel(char* __restrict__ ws, float* __restrict__ out)
{
  int id = blockIdx.x*256 + threadIdx.x;   // 8192
  const float* c = (const float*)(ws + WS_CARRY);
  size_t ob = (size_t)B_*T_*K_;
  out[ob + id]         = c[id];            // n_t
  out[ob + 8192 + id]  = c[8192+id];       // d_t
  out[ob + 16384 + id] = c[16384+id];      // h_t
  out[ob + 24576 + id] = c[24576+id]*LN2;  // a_new (unscale)
}

extern "C" void kernel_launch(void* const* d_in, const int* in_sizes, int n_in,
                              void* d_out, int out_size, void* d_ws, size_t ws_size,
                              hipStream_t stream)
{
  const float* x   = (const float*)d_in[0];
  const float* n0  = (const float*)d_in[1];
  const float* d0  = (const float*)d_in[2];
  const float* h0  = (const float*)d_in[3];
  const float* am0 = (const float*)d_in[4];
  const float* g_w = (const float*)d_in[5];
  const float* g_b = (const float*)d_in[6];
  const float* u_w = (const float*)d_in[7];
  const float* u_b = (const float*)d_in[8];
  const float* a_w = (const float*)d_in[9];
  const float* o_w = (const float*)d_in[10];
  const float* o_b = (const float*)d_in[11];
  float* out = (float*)d_out;
  char* ws = (char*)d_ws;

  unsigned Tc = 4096;
  while (Tc > 64 && (size_t)WS_DYN + 65536ull*Tc > ws_size) Tc >>= 1;
  if ((size_t)WS_DYN + 65536ull*Tc > ws_size) return;
  int lgTc  = __builtin_ctz(Tc);
  int lgT16 = lgTc - 4;
  int nch   = T_ / (int)Tc;

  hipLaunchKernelGGL(scale_kernel, dim3(2), dim3(256), 0, stream, g_w, a_w, ws);
  hipLaunchKernelGGL(pack_kernel, dim3(99), dim3(256), 0, stream,
                     g_w, u_w, a_w, g_b, u_b, o_w, ws);
  hipLaunchKernelGGL(init_kernel, dim3(32), dim3(256), 0, stream,
                     n0, d0, h0, am0, ws);
  for (int c0=0; c0<nch; ++c0){
    int t0 = c0*(int)Tc;
    hipLaunchKernelGGL(ph1_kernel, dim3(B_*(int)Tc/64), dim3(256), 0, stream,
                       x, ws, t0, (int)Tc, lgT16);
    hipLaunchKernelGGL(scan_kernel, dim3(B_), dim3(256), 0, stream,
                       ws, (int)Tc);
    hipLaunchKernelGGL(ph3_kernel, dim3(B_*(int)Tc/64), dim3(256), 0, stream,
                       o_b, ws, out, t0, (int)Tc, lgT16);
  }
  hipLaunchKernelGGL(fin_kernel, dim3(32), dim3(256), 0, stream, ws, out);
}

// Round 6
// 2107.676 us; speedup vs baseline: 1.8469x; 1.8469x over previous
//
#include <hip/hip_runtime.h>
#include <hip/hip_fp16.h>

#define B_ 32
#define T_ 4096
#define F_ 128
#define C_ 256
#define K_ 128
#define FC_ 384

typedef __attribute__((ext_vector_type(8))) short s8v;
typedef __attribute__((ext_vector_type(4))) float f4v;
typedef __attribute__((ext_vector_type(4))) int   i4v;

#define MFMA16(a,b,c) __builtin_amdgcn_mfma_f32_16x16x32_bf16((a),(b),(c),0,0,0)
#define MFMAI8(a,b,c) __builtin_amdgcn_mfma_i32_16x16x64_i8((a),(b),(c),0,0,0)

#define LOG2E  1.442695041f
#define LOG2E2 2.885390082f
#define LN2    0.6931471806f

// ---- workspace layout (bytes) ----
#define WS_WSCAN 0u        // i8 scan frags: 8192 * 16 = 131072
#define WS_SMAX  131072u   // 512 f32 per-column |w|max (g:0-255, a:256-511)
#define WS_W1F   262144u   // 12288 * 16 = 196608
#define WS_OWF   458752u   // 4096 * 16 = 65536
#define WS_BIAS1 524288u   // 768 * 4 = 3072
#define WS_CARRY 527360u   // n,d,h,am(scaled by log2e) : 4 * 8192 f32 = 131072
#define WS_DYN   658432u   // pre chunk (49152*Tc B) then hall chunk (16384*Tc B)

__device__ __forceinline__ unsigned short f2bf(float f){
  unsigned u = __float_as_uint(f);
  u += 0x7fffu + ((u>>16)&1u);     // round-to-nearest-even
  return (unsigned short)(u>>16);
}
__device__ __forceinline__ float h2f(unsigned short s){
  __half_raw r; r.x = s; return __half2float((__half)r);
}
__device__ __forceinline__ float fexp2(float x){
#if __has_builtin(__builtin_amdgcn_exp2f)
  return __builtin_amdgcn_exp2f(x);
#else
  return __expf(x*0.69314718056f);
#endif
}

// ---------------- per-column |w|max for i8 quant of scan weights ----------------
__global__ __launch_bounds__(256) void scale_kernel(
    const float* __restrict__ g_w, const float* __restrict__ a_w, char* __restrict__ ws)
{
  int id = blockIdx.x*256 + threadIdx.x;     // 512
  if (id >= 512) return;
  const float* src = (id < 256) ? g_w : a_w;
  int c = id & 255;
  float m = 0.0f;
  #pragma unroll 8
  for (int k=0;k<256;++k) m = fmaxf(m, fabsf(src[c*FC_ + F_ + k]));
  ((float*)(ws + WS_SMAX))[id] = fmaxf(m, 1e-30f);
}

// ---------------- weight packing ----------------
// i8 scan frag (16x16x64): lane l, byte j holds W_i8[k = kc*64 + (l>>4)*16 + j][n=16tp+(l&15)]
// (A uses the SAME (lane-group,byte)->k map, so the HW's true map cancels — bijection
// argument; end-to-end verified in R2: absmax 8.0 identical to the bf16 version.)
__global__ __launch_bounds__(256) void pack_kernel(
    const float* __restrict__ g_w, const float* __restrict__ u_w, const float* __restrict__ a_w,
    const float* __restrict__ g_b, const float* __restrict__ u_b, const float* __restrict__ o_w,
    char* __restrict__ ws)
{
  int id = blockIdx.x*256 + threadIdx.x;
  const float* smax = (const float*)(ws + WS_SMAX);
  unsigned short* w1f   = (unsigned short*)(ws + WS_W1F);
  unsigned short* owf   = (unsigned short*)(ws + WS_OWF);
  float* bias1          = (float*)(ws + WS_BIAS1);
  if (id < 8192){
    // idx = (((wv*2+mat)*4+tp)*4+kc)*64 + l ; channel c = 64wv+16tp+(l&15)
    int l = id & 63, kc = (id>>6)&3, tp = (id>>8)&3, mat = (id>>10)&1, wv = id>>11;
    int c  = wv*64 + tp*16 + (l&15);
    int kb = kc*64 + (l>>4)*16;
    const float* src = mat ? a_w : g_w;
    float inv = 127.0f / smax[mat*256 + c];
    int w32[4] = {0,0,0,0};
    #pragma unroll
    for (int j=0;j<16;++j){
      int q8 = __float2int_rn(src[c*FC_ + F_ + kb + j] * inv);
      w32[j>>2] |= (q8 & 0xff) << (8*(j&3));
    }
    int* dst = (int*)(ws + WS_WSCAN) + id*4;
    dst[0]=w32[0]; dst[1]=w32[1]; dst[2]=w32[2]; dst[3]=w32[3];
  } else if (id < 8192+12288){
    // ph1 weights rows n: [0,256)=u_w, [256,512)=g_w x-part (*2log2e), [512,768)=a_w x-part (*log2e)
    int id2 = id - 8192;
    int l = id2 & 63, kc = (id2>>6)&3, nt = id2>>8;
    int n = nt*16 + (l&15);
    int kb = kc*32 + (l>>4)*8;
    float sc = (n < 256) ? 1.0f : (n < 512) ? LOG2E2 : LOG2E;
    #pragma unroll
    for (int j=0;j<8;++j){
      int k = kb + j;
      float v = (n < 256) ? u_w[n*F_ + k]
              : (n < 512) ? g_w[(n-256)*FC_ + k]
                          : a_w[(n-512)*FC_ + k];
      w1f[id2*8+j] = f2bf(v*sc);
    }
  } else if (id < 8192+12288+4096){
    int id3 = id - (8192+12288);
    int l = id3 & 63, kc = (id3>>6)&7, nt = id3>>9;
    int n = nt*16 + (l&15);
    int kb = kc*32 + (l>>4)*8;
    #pragma unroll
    for (int j=0;j<8;++j)
      owf[id3*8+j] = f2bf(o_w[n*C_ + kb + j]);
  } else if (id < 8192+12288+4096+768){
    int i = id - (8192+12288+4096);
    bias1[i] = (i<256) ? u_b[i] : (i<512 ? g_b[i-256]*LOG2E2 : 0.0f);
  }
}

// ---------------- init: carry <- initial state (a_max scaled by log2e) ----------------
__global__ __launch_bounds__(256) void init_kernel(
    const float* __restrict__ n0, const float* __restrict__ d0,
    const float* __restrict__ h0, const float* __restrict__ am0, char* __restrict__ ws)
{
  int id = blockIdx.x*256 + threadIdx.x;   // 8192
  float* c = (float*)(ws + WS_CARRY);
  c[id]        = n0[id];
  c[8192+id]   = d0[id];
  c[16384+id]  = h0[id];
  c[24576+id]  = am0[id]*LOG2E;
}

// ---------------- ph1: pre = x @ [u_w; g_w_x*2log2e; a_w_x*log2e]^T + bias (fp16) --------
__global__ __launch_bounds__(256) void ph1_kernel(const float* __restrict__ x, char* __restrict__ ws,
                                                  int t0, int Tc, int lgT16)
{
  const s8v* w1f = (const s8v*)(ws + WS_W1F);
  const float* bias1 = (const float*)(ws + WS_BIAS1);
  __half* pre = (__half*)(ws + WS_DYN);
  int tid = threadIdx.x;
  int wv = tid>>6, l = tid&63, q = l>>4, col = l&15;
  int wid = blockIdx.x*4 + wv;
  int b  = wid >> lgT16;
  int tb = (wid & ((1<<lgT16)-1))*16;
  s8v af[4];
  const float* xr = x + ((size_t)b*T_ + t0 + tb + col)*F_ + q*8;
  #pragma unroll
  for (int kc=0;kc<4;++kc){
    const float* p = xr + kc*32;
    float4 p0 = *(const float4*)(p);
    float4 p1 = *(const float4*)(p+4);
    s8v a;
    a[0]=(short)f2bf(p0.x); a[1]=(short)f2bf(p0.y); a[2]=(short)f2bf(p0.z); a[3]=(short)f2bf(p0.w);
    a[4]=(short)f2bf(p1.x); a[5]=(short)f2bf(p1.y); a[6]=(short)f2bf(p1.z); a[7]=(short)f2bf(p1.w);
    af[kc]=a;
  }
  for (int nt=0;nt<48;++nt){
    f4v acc = {0.f,0.f,0.f,0.f};
    #pragma unroll
    for (int kc=0;kc<4;++kc)
      acc = MFMA16(af[kc], w1f[(nt*4+kc)*64 + l], acc);
    int cg = nt*16 + col;
    float bs = bias1[cg];
    #pragma unroll
    for (int i=0;i<4;++i){
      int rl = tb + q*4 + i;
      pre[(size_t)(b*Tc + rl)*768 + cg] = __float2half(acc[i] + bs);
    }
  }
}

// ---------------- scan: sequential recurrence, 1 batch row per block ----------------
// R6: revert to R2's proven i8-MFMA structure (weights resident as MFMA B-frags in
// AGPRs — the ONLY residency scheme the allocator honors; R3/R5's VGPR plans spilled,
// VGPR_Count 84 both times). On top of R2, split the MFMA stream: all 16 g-MFMAs,
// then (prefetch consume/refill — MFMA-independent), then 16 a-MFMAs, tail last.
// One wave/SIMD issues an MFMA every ~16 cyc with ~14 idle issue slots — the VALU
// work placed between/after the g-block fills those gaps instead of serializing
// after all 32 MFMAs (R2 lost ~350 cyc/step to that serialization).
__global__ __launch_bounds__(256,1) void scan_kernel(char* __restrict__ ws, int Tc)
{
  __shared__ __align__(16) char h8buf[2][256];
  const i4v* wp = (const i4v*)(ws + WS_WSCAN);
  const float* smax = (const float*)(ws + WS_SMAX);
  const unsigned short* prbu = (const unsigned short*)(ws + WS_DYN);
  unsigned short* hall = (unsigned short*)(ws + WS_DYN + 49152u*(unsigned)Tc);
  float* carry = (float*)(ws + WS_CARRY);
  int tid = threadIdx.x;
  int wv = tid>>6, l = tid&63, q = l>>4, col = l&15;
  int b = blockIdx.x;
  int c = wv*64 + q*16 + col;          // this lane's channel

  // resident i8 weights: 32 B-frags = 128 regs/wave (MFMA operands -> AGPRs)
  i4v wg[4][4], wa[4][4];
  #pragma unroll
  for (int tp=0;tp<4;++tp)
    #pragma unroll
    for (int kc=0;kc<4;++kc){
      wg[tp][kc] = wp[(((wv*2+0)*4+tp)*4+kc)*64 + l];
      wa[tp][kc] = wp[(((wv*2+1)*4+tp)*4+kc)*64 + l];
    }
  float gsc = smax[c]     * (LOG2E2/16129.0f);   // maxg/(127*127) * 2log2e
  float asc = smax[256+c] * (LOG2E /16129.0f);

  int gi = b*C_ + c;
  float cn = carry[gi], cd = carry[8192+gi], cm = carry[24576+gi];
  h8buf[0][c] = (char)__float2int_rn(carry[16384+gi]*127.0f);
  __syncthreads();

  const size_t prb = (size_t)b*Tc*768;
  unsigned short* hrow = hall + (size_t)b*Tc*C_ + c;

  // prefetch pre for t=0..3 (4-deep; loads stay in flight across lgkm-only barriers)
  unsigned short su[4], sg[4], sa[4];
  #pragma unroll
  for (int i=0;i<4;++i){
    size_t o = prb + (size_t)i*768;
    su[i]=prbu[o + c]; sg[i]=prbu[o + 256+c]; sa[i]=prbu[o + 512+c];
  }

  #pragma unroll 1
  for (int t=0;t<Tc;t+=4){
    #pragma unroll
    for (int ph=0; ph<4; ++ph){
      int s = t + ph;
      const char* hc = h8buf[ph&1];
      char* hn = h8buf[(ph&1)^1];
      const i4v* hv4 = (const i4v*)hc;
      // all 4 A-frag ds_read_b128 up front (broadcast within 16-lane groups)
      i4v af0 = hv4[0*4+q], af1 = hv4[1*4+q], af2 = hv4[2*4+q], af3 = hv4[3*4+q];
      // ---- 16 g-MFMAs (4 chains x 4 deep, round-robin) ----
      i4v aG0={0,0,0,0}, aG1={0,0,0,0}, aG2={0,0,0,0}, aG3={0,0,0,0};
      aG0=MFMAI8(af0,wg[0][0],aG0); aG1=MFMAI8(af0,wg[1][0],aG1);
      aG2=MFMAI8(af0,wg[2][0],aG2); aG3=MFMAI8(af0,wg[3][0],aG3);
      aG0=MFMAI8(af1,wg[0][1],aG0); aG1=MFMAI8(af1,wg[1][1],aG1);
      aG2=MFMAI8(af1,wg[2][1],aG2); aG3=MFMAI8(af1,wg[3][1],aG3);
      aG0=MFMAI8(af2,wg[0][2],aG0); aG1=MFMAI8(af2,wg[1][2],aG1);
      aG2=MFMAI8(af2,wg[2][2],aG2); aG3=MFMAI8(af2,wg[3][2],aG3);
      aG0=MFMAI8(af3,wg[0][3],aG0); aG1=MFMAI8(af3,wg[1][3],aG1);
      aG2=MFMAI8(af3,wg[2][3],aG2); aG3=MFMAI8(af3,wg[3][3],aG3);
      // ---- MFMA-independent work: consume slot ph + refill for s+4 ----
      float fu = h2f(su[ph]), fg = h2f(sg[ph]), fa = h2f(sa[ph]);
      {
        int nxt = (s+4 < Tc) ? s+4 : s;
        size_t o = prb + (size_t)nxt*768;
        su[ph]=prbu[o + c]; sg[ph]=prbu[o + 256+c]; sa[ph]=prbu[o + 512+c];
      }
      // ---- 16 a-MFMAs (g-chains drain under this issue stream) ----
      i4v aA0={0,0,0,0}, aA1={0,0,0,0}, aA2={0,0,0,0}, aA3={0,0,0,0};
      aA0=MFMAI8(af0,wa[0][0],aA0); aA1=MFMAI8(af0,wa[1][0],aA1);
      aA2=MFMAI8(af0,wa[2][0],aA2); aA3=MFMAI8(af0,wa[3][0],aA3);
      aA0=MFMAI8(af1,wa[0][1],aA0); aA1=MFMAI8(af1,wa[1][1],aA1);
      aA2=MFMAI8(af1,wa[2][1],aA2); aA3=MFMAI8(af1,wa[3][1],aA3);
      aA0=MFMAI8(af2,wa[0][2],aA0); aA1=MFMAI8(af2,wa[1][2],aA1);
      aA2=MFMAI8(af2,wa[2][2],aA2); aA3=MFMAI8(af2,wa[3][2],aA3);
      aA0=MFMAI8(af3,wa[0][3],aA0); aA1=MFMAI8(af3,wa[1][3],aA1);
      aA2=MFMAI8(af3,wa[2][3],aA2); aA3=MFMAI8(af3,wa[3][3],aA3);
      // ---- g select + z (g accumulators long drained) ----
      int g01 = (q&1)? aG1[0] : aG0[0];
      int g23 = (q&1)? aG3[0] : aG2[0];
      float g = (float)((q&2)? g23 : g01) * gsc + fg;     // = 2log2e * g_raw
      float z = fu * (1.0f - 2.0f*__builtin_amdgcn_rcpf(fexp2(g) + 1.0f));  // fu*tanh(g_raw)
      // ---- a select + recurrence ----
      int a01 = (q&1)? aA1[0] : aA0[0];
      int a23 = (q&1)? aA3[0] : aA2[0];
      float a = (float)((q&2)? a23 : a01) * asc + fa;     // = log2e * a_raw
      float anew = fmaxf(cm,a);
      float dmin = fminf(cm,a);
      float e = fexp2(dmin-anew);      // one side is exp(0)=1
      bool ge = (a>=cm);
      float ed = ge? e : 1.0f;
      float es = ge? 1.0f : e;
      cn = cn*ed + z*es;
      cd = fmaf(cd,ed,es);
      float hv = 1.0f - 2.0f*__builtin_amdgcn_rcpf(fexp2(LOG2E2*(cn*__builtin_amdgcn_rcpf(cd))) + 1.0f);
      cm = anew;
      hn[c] = (char)__float2int_rn(hv*127.0f);
      hrow[(size_t)s*C_] = f2bf(hv);
      // LDS-only drain + raw barrier: global loads/stores stay in flight.
      asm volatile("s_waitcnt lgkmcnt(0)" ::: "memory");
      __builtin_amdgcn_s_barrier();
      asm volatile("" ::: "memory");
    }
  }
  // write back carry
  carry[gi] = cn; carry[8192+gi] = cd; carry[24576+gi] = cm;
  carry[16384+gi] = 1.0f - 2.0f*__builtin_amdgcn_rcpf(fexp2(LOG2E2*(cn*__builtin_amdgcn_rcpf(cd))) + 1.0f);
}

// ---------------- ph3: outs = h @ o_w^T + o_b ----------------
__global__ __launch_bounds__(256) void ph3_kernel(const float* __restrict__ o_b,
                                                  char* __restrict__ ws, float* __restrict__ out,
                                                  int t0, int Tc, int lgT16)
{
  const s8v* owf = (const s8v*)(ws + WS_OWF);
  const unsigned short* hall = (const unsigned short*)(ws + WS_DYN + 49152u*(unsigned)Tc);
  int tid = threadIdx.x;
  int wv = tid>>6, l = tid&63, q=l>>4, col=l&15;
  int wid = blockIdx.x*4 + wv;
  int bb = wid >> lgT16;
  int tt = (wid & ((1<<lgT16)-1))*16;
  const unsigned short* src = hall + ((size_t)bb*Tc + tt)*C_;
  s8v af[8];
  #pragma unroll
  for (int kc=0;kc<8;++kc)
    af[kc] = *(const s8v*)(src + (size_t)col*C_ + kc*32 + q*8);
  #pragma unroll
  for (int nt=0;nt<8;++nt){
    f4v acc={0.f,0.f,0.f,0.f};
    #pragma unroll
    for (int kc=0;kc<8;++kc)
      acc = MFMA16(af[kc], owf[(nt*8+kc)*64 + l], acc);
    int k = nt*16+col;
    float bs = o_b[k];
    #pragma unroll
    for (int i=0;i<4;++i)
      out[((size_t)bb*T_ + t0 + tt + q*4 + i)*K_ + k] = acc[i] + bs;
  }
}

// ---------------- finalize: final states -> out tail (unscale a_max) ----------------
__global__ __launch_bounds__(256) void fin_kernel(char* __restrict__ ws, float* __restrict__ out)
{
  int id = blockIdx.x*256 + threadIdx.x;   // 8192
  const float* c = (const float*)(ws + WS_CARRY);
  size_t ob = (size_t)B_*T_*K_;
  out[ob + id]         = c[id];            // n_t
  out[ob + 8192 + id]  = c[8192+id];       // d_t
  out[ob + 16384 + id] = c[16384+id];      // h_t
  out[ob + 24576 + id] = c[24576+id]*LN2;  // a_new (unscale)
}

extern "C" void kernel_launch(void* const* d_in, const int* in_sizes, int n_in,
                              void* d_out, int out_size, void* d_ws, size_t ws_size,
                              hipStream_t stream)
{
  const float* x   = (const float*)d_in[0];
  const float* n0  = (const float*)d_in[1];
  const float* d0  = (const float*)d_in[2];
  const float* h0  = (const float*)d_in[3];
  const float* am0 = (const float*)d_in[4];
  const float* g_w = (const float*)d_in[5];
  const float* g_b = (const float*)d_in[6];
  const float* u_w = (const float*)d_in[7];
  const float* u_b = (const float*)d_in[8];
  const float* a_w = (const float*)d_in[9];
  const float* o_w = (const float*)d_in[10];
  const float* o_b = (const float*)d_in[11];
  float* out = (float*)d_out;
  char* ws = (char*)d_ws;

  unsigned Tc = 4096;
  while (Tc > 64 && (size_t)WS_DYN + 65536ull*Tc > ws_size) Tc >>= 1;
  if ((size_t)WS_DYN + 65536ull*Tc > ws_size) return;
  int lgTc  = __builtin_ctz(Tc);
  int lgT16 = lgTc - 4;
  int nch   = T_ / (int)Tc;

  hipLaunchKernelGGL(scale_kernel, dim3(2), dim3(256), 0, stream, g_w, a_w, ws);
  hipLaunchKernelGGL(pack_kernel, dim3(99), dim3(256), 0, stream,
                     g_w, u_w, a_w, g_b, u_b, o_w, ws);
  hipLaunchKernelGGL(init_kernel, dim3(32), dim3(256), 0, stream,
                     n0, d0, h0, am0, ws);
  for (int c0=0; c0<nch; ++c0){
    int t0 = c0*(int)Tc;
    hipLaunchKernelGGL(ph1_kernel, dim3(B_*(int)Tc/64), dim3(256), 0, stream,
                       x, ws, t0, (int)Tc, lgT16);
    hipLaunchKernelGGL(scan_kernel, dim3(B_), dim3(256), 0, stream,
                       ws, (int)Tc);
    hipLaunchKernelGGL(ph3_kernel, dim3(B_*(int)Tc/64), dim3(256), 0, stream,
                       o_b, ws, out, t0, (int)Tc, lgT16);
  }
  hipLaunchKernelGGL(fin_kernel, dim3(32), dim3(256), 0, stream, ws, out);
}